// Round 5
// baseline (1118.939 us; speedup 1.0000x reference)
//
#include <hip/hip_runtime.h>
#include <hip/hip_bf16.h>
#include <math.h>

#define NB   256
#define NIMG 128
#define DIM  768
#define NE   3
#define NS   44
#define NH   1024
#define ESL  132          // NE*NS
#define NTOK (NB*NIMG)    // 32768
#define MAXSLOTS 88
#define BIGI (1 << 30)
#define KPAD 160          // combine K padded to mult of 32

typedef __bf16 bf16x8 __attribute__((ext_vector_type(8)));
typedef float f32x4 __attribute__((ext_vector_type(4)));
typedef const __attribute__((address_space(1))) void* gas_t;
typedef __attribute__((address_space(3))) void* las_t;

// ---------------- helpers ----------------
__device__ __forceinline__ float gelu_f(float v) {
    return 0.5f * v * (1.0f + erff(v * 0.70710678118654752f));
}

__device__ __forceinline__ float block_reduce_sum256(float v, float* red) {
    int tid = threadIdx.x;
    red[tid] = v;
    __syncthreads();
    for (int s = 128; s > 0; s >>= 1) {
        if (tid < s) red[tid] += red[tid + s];
        __syncthreads();
    }
    float r = red[0];
    __syncthreads();
    return r;
}

// ---------------- repack mu: (e,d,88) -> Bt[r=e*44+s][d], bf16, padded to 256 rows ----------------
__global__ void repack_mu_k(const float* __restrict__ mu, __hip_bfloat16* __restrict__ bt) {
    int idx = blockIdx.x * 256 + threadIdx.x;
    if (idx >= 256 * DIM) return;
    int r = idx / DIM, d = idx - r * DIM;
    float v = 0.f;
    if (r < ESL) {
        int e = r / NS, s = r - e * NS;
        v = mu[((size_t)e * DIM + d) * MAXSLOTS + s];
    }
    bt[idx] = __float2bfloat16(v);
}

// ---------------- fp32 (R x Cc) -> bf16 (Cc x R) transpose, batched, general strides ----------------
__global__ void transpose_bf16_k(const float* __restrict__ in, __hip_bfloat16* __restrict__ outp,
                                 int R, int Cc, long long inBS, long long outBS) {
    __shared__ float t[32][33];
    in   += (long long)blockIdx.z * inBS;
    outp += (long long)blockIdx.z * outBS;
    int c0 = blockIdx.x * 32, r0 = blockIdx.y * 32;
    int tx = threadIdx.x, ty = threadIdx.y;   // 32 x 8
    for (int i = 0; i < 32; i += 8) {
        int r = r0 + ty + i, c = c0 + tx;
        t[ty + i][tx] = (r < R && c < Cc) ? in[(size_t)r * Cc + c] : 0.f;
    }
    __syncthreads();
    for (int i = 0; i < 32; i += 8) {
        int r = c0 + ty + i, c = r0 + tx;     // out is Cc x R
        if (r < Cc && c < R) outp[(size_t)r * R + c] = __float2bfloat16(t[tx][ty + i]);
    }
}

// ---------------- cls rows -> bf16 copy ----------------
__global__ void cls_bf16_k(const float* __restrict__ x, __hip_bfloat16* __restrict__ cls16) {
    int idx = blockIdx.x * 256 + threadIdx.x;
    if (idx >= NB * DIM) return;
    int b = idx / DIM, j = idx - b * DIM;
    cls16[idx] = __float2bfloat16(x[(size_t)b * 129 * DIM + j]);
}

// ---------------- zero the K-pad cols [ESL, KPAD) of slot_outT [b][d][KPAD] ----------------
__global__ void zero_pad_k(__hip_bfloat16* __restrict__ p) {
    const int per = KPAD - ESL;                 // 28
    const int total = NB * DIM * per;           // 5,505,024
    int idx = blockIdx.x * 256 + threadIdx.x;
    if (idx >= total) return;
    int bd = idx / per, k = idx - bd * per;
    p[(size_t)bd * KPAD + ESL + k] = __float2bfloat16(0.f);
}

// ---------------- slot_bias[b,:] = cls@vsg_w[:768] + af*vsg_w[768] + vsg_b ----------------
__global__ void slot_bias_k(const float* __restrict__ x, const float* __restrict__ aw,
                            const float* __restrict__ vsg_w, const float* __restrict__ vsg_b,
                            float* __restrict__ slot_bias) {
    __shared__ float red[256];
    __shared__ float cls[DIM];
    int b = blockIdx.x, tid = threadIdx.x;
    float a = (tid < NIMG) ? aw[b * NIMG + tid] : 0.f;
    float af = block_reduce_sum256(a, red) * (1.0f / NIMG);
    for (int j = tid; j < DIM; j += 256) cls[j] = x[(size_t)b * 129 * DIM + j];
    __syncthreads();
    int j0 = tid, j1 = tid + 256, j2 = tid + 512;
    float acc0 = 0.f, acc1 = 0.f, acc2 = 0.f;
    for (int d = 0; d < DIM; ++d) {
        float c = cls[d];
        const float* wr = vsg_w + (size_t)d * DIM;
        acc0 = fmaf(c, wr[j0], acc0);
        acc1 = fmaf(c, wr[j1], acc1);
        acc2 = fmaf(c, wr[j2], acc2);
    }
    const float* wl = vsg_w + (size_t)DIM * DIM;
    float* out = slot_bias + (size_t)b * DIM;
    out[j0] = acc0 + vsg_b[j0] + af * wl[j0];
    out[j1] = acc1 + vsg_b[j1] + af * wl[j1];
    out[j2] = acc2 + vsg_b[j2] + af * wl[j2];
}

// ---------------- LayerNorm (bf16 out) + t2 = dot(img_n, slot_bias[b]) ----------------
__global__ void ln_t2_k(const float* __restrict__ x, const float* __restrict__ gamma,
                        const float* __restrict__ beta, const float* __restrict__ slot_bias,
                        __hip_bfloat16* __restrict__ img_n, float* __restrict__ t2) {
    __shared__ float red[256];
    int tok = blockIdx.x;
    int b = tok >> 7, n = tok & 127;
    int tid = threadIdx.x;
    const float* row = x + ((size_t)b * 129 + 1 + n) * DIM;
    float v0 = row[tid], v1 = row[tid + 256], v2 = row[tid + 512];
    float s  = block_reduce_sum256(v0 + v1 + v2, red);
    float ss = block_reduce_sum256(v0*v0 + v1*v1 + v2*v2, red);
    float mean = s * (1.0f / DIM);
    float var  = ss * (1.0f / DIM) - mean * mean;
    float inv  = rsqrtf(var + 1e-5f);
    const float* sb = slot_bias + (size_t)b * DIM;
    __hip_bfloat16* orow = img_n + (size_t)tok * DIM;
    float tacc = 0.f;
    int j = tid;
    float y0 = (v0 - mean) * inv * gamma[j] + beta[j]; orow[j] = __float2bfloat16(y0); tacc = fmaf(y0, sb[j], tacc);
    j = tid + 256;
    float y1 = (v1 - mean) * inv * gamma[j] + beta[j]; orow[j] = __float2bfloat16(y1); tacc = fmaf(y1, sb[j], tacc);
    j = tid + 512;
    float y2 = (v2 - mean) * inv * gamma[j] + beta[j]; orow[j] = __float2bfloat16(y2); tacc = fmaf(y2, sb[j], tacc);
    float t = block_reduce_sum256(tacc, red);
    if (tid == 0) t2[tok] = t;
}

// ---------------- masked logits: L = (e==sel) ? scale*(t1+t2) : 0 ----------------
__global__ void mask_k(float* __restrict__ L, const float* __restrict__ t2,
                       const float* __restrict__ aw, const float* __restrict__ scale) {
    int idx = blockIdx.x * 256 + threadIdx.x;
    if (idx >= NTOK * ESL) return;
    int tok = idx / ESL, r = idx - tok * ESL;
    int e = r / NS;
    float a = aw[tok];
    int sel = (a > 0.7f) ? 0 : ((a >= 0.3f) ? 1 : 2);
    float v = 0.f;
    if (e == sel) v = scale[0] * (L[idx] + t2[tok]);
    L[idx] = v;
}

// ---------------- dispatch softmax over n (axis=1), bf16 out transposed [b, es, n] ----------------
__global__ void dispatch_k(const float* __restrict__ L, __hip_bfloat16* __restrict__ dT16) {
    __shared__ float red[128];
    int es = blockIdx.x, b = blockIdx.y, tid = threadIdx.x;  // 128 threads
    float v = L[((size_t)(b * NIMG + tid)) * ESL + es];
    red[tid] = v; __syncthreads();
    for (int s = 64; s > 0; s >>= 1) { if (tid < s) red[tid] = fmaxf(red[tid], red[tid + s]); __syncthreads(); }
    float mx = red[0]; __syncthreads();
    float e = __expf(v - mx);
    red[tid] = e; __syncthreads();
    for (int s = 64; s > 0; s >>= 1) { if (tid < s) red[tid] += red[tid + s]; __syncthreads(); }
    float sum = red[0];
    dT16[((size_t)b * ESL + es) * NIMG + tid] = __float2bfloat16(e / sum);
}

// ---------------- combine softmax over es (132) per token, bf16 out padded to 160 ----------------
__global__ void combine_k(const float* __restrict__ L, __hip_bfloat16* __restrict__ C) {
    int tok = blockIdx.x, lane = threadIdx.x;  // 64 threads
    const float* row = L + (size_t)tok * ESL;
    float v0 = row[lane], v1 = row[lane + 64];
    bool has2 = lane < (ESL - 128);
    float v2 = has2 ? row[lane + 128] : -1e30f;
    float m = fmaxf(fmaxf(v0, v1), v2);
    for (int o = 32; o > 0; o >>= 1) m = fmaxf(m, __shfl_xor(m, o));
    float e0 = __expf(v0 - m), e1 = __expf(v1 - m);
    float e2 = has2 ? __expf(v2 - m) : 0.f;
    float s = e0 + e1 + e2;
    for (int o = 32; o > 0; o >>= 1) s += __shfl_xor(s, o);
    float inv = 1.0f / s;
    __hip_bfloat16* orow = C + (size_t)tok * KPAD;
    orow[lane] = __float2bfloat16(e0 * inv);
    orow[lane + 64] = __float2bfloat16(e1 * inv);
    if (has2) orow[lane + 128] = __float2bfloat16(e2 * inv);
    else if (lane < KPAD - 128) orow[lane + 128] = __float2bfloat16(0.f);  // zero K-pad
}

// ---------------- bf16 MFMA GEMM v6: 128x256 tile, 64x128 wave tile, dbuf counted vmcnt, XCD swizzle ----------------
// C = act(A @ Bt^T + bias). A: Mrows x lda bf16 (M-tile 128); Bt: Nrows x ldb bf16 (N-tile 256).
// 4 waves in 2x2; wave tile 64(M) x 128(N): frag reads (4+8)x16B per 32 MFMA
// -> 384 B LDS-read per MFMA at block level (vs 512 for 64x64 wave tiles).
// Grid is 1D (nx*ny*nz), bijective XCD-chunk swizzle (m204).
// order=0: work = bx + nx*by + nx*ny*bz (x fastest); order=1: y fastest.
// ctrans=0 (normal):   off = z*cBS + ((row/cSub)*cOuter + row%cSub)*ldc + col ; bias[col]
// ctrans=1 (row-T):    off = z*cBS + (row/cSub)*cOuter + row%cSub + col*ldc  ; bias[col]
// ctrans=2 (col-T):    off = z*cBS + (col/cSub)*cOuter + col%cSub + row*ldc  ; bias[row]
__global__ __launch_bounds__(256, 2)
void mfma2_k(const __hip_bfloat16* __restrict__ A_, long long aBS, int lda, int Mrows,
             const __hip_bfloat16* __restrict__ Bt_, long long bBS, int ldb, int Nrows,
             const float* __restrict__ bias, long long biasBS,
             void* __restrict__ Cv, long long cBS, int ldc, int cSub, long long cOuter,
             int Mlim, int Nlim, int K, int act, int out_bf16, int ctrans,
             int nx, int ny, int order)
{
    // ---- bijective XCD-chunk swizzle ----
    int nwg = gridDim.x;
    int hw = blockIdx.x;
    int q = nwg >> 3, r = nwg & 7;
    int xcd = hw & 7, off0 = hw >> 3;
    int wid = (xcd < r ? xcd * (q + 1) : r * (q + 1) + (xcd - r) * q) + off0;
    int pp = nx * ny;
    int bz = wid / pp;
    int rm = wid - bz * pp;
    int bx, by;
    if (order == 0) { by = rm / nx; bx = rm - by * nx; }
    else            { bx = rm / ny; by = rm - bx * ny; }

    const unsigned short* A  = (const unsigned short*)A_  + (long long)bz * aBS;
    const unsigned short* Bt = (const unsigned short*)Bt_ + (long long)bz * bBS;
    if (bias) bias += (long long)bz * biasBS;
    long long cbase = (long long)bz * cBS;

    __shared__ unsigned short As[2][128 * 32];   // 2 x 8 KB
    __shared__ unsigned short Bs[2][256 * 32];   // 2 x 16 KB

    int tid = threadIdx.x;
    int lane = tid & 63, wv = tid >> 6;
    int m0 = by * 128, n0 = bx * 256;

    // staging: A = 8 wave-instrs total (2/wave), B = 16 (4/wave).
    // instr j covers LDS bytes [j*1024, (j+1)*1024): lane l -> base + l*16 (HW per-lane).
    // position p = j*64+l -> tile row r = p>>2, LDS chunk cl = p&3,
    // global chunk cg = cl ^ ((r>>1)&3)   (swizzle; makes frag ds_read_b128 2-way max)
    const unsigned short* ga[2];
    const unsigned short* gb[4];
    int loffA[2], loffB[4];
#pragma unroll
    for (int i = 0; i < 2; ++i) {
        int j = wv * 2 + i;
        int p = j * 64 + lane;
        int rr = p >> 2;
        int cg = (p & 3) ^ ((rr >> 1) & 3);
        int ra = m0 + rr; if (ra > Mrows - 1) ra = Mrows - 1;
        ga[i] = A + (long long)ra * lda + cg * 8;
        loffA[i] = j * 512;
    }
#pragma unroll
    for (int i = 0; i < 4; ++i) {
        int j = wv * 4 + i;
        int p = j * 64 + lane;
        int rr = p >> 2;
        int cg = (p & 3) ^ ((rr >> 1) & 3);
        int rb = n0 + rr; if (rb > Nrows - 1) rb = Nrows - 1;
        gb[i] = Bt + (long long)rb * ldb + cg * 8;
        loffB[i] = j * 512;
    }

    int lrow = lane & 15, quad = lane >> 4;
    int wm = (wv >> 1) * 64, wn = (wv & 1) * 128;
    int offA[4], offB[8];
#pragma unroll
    for (int i = 0; i < 4; ++i) {
        int rowa = wm + i * 16 + lrow;
        offA[i] = rowa * 32 + ((quad ^ ((rowa >> 1) & 3)) * 8);
    }
#pragma unroll
    for (int i = 0; i < 8; ++i) {
        int rowb = wn + i * 16 + lrow;
        offB[i] = rowb * 32 + ((quad ^ ((rowb >> 1) & 3)) * 8);
    }

    f32x4 acc[4][8] = {};
    int nt = K >> 5;

    // prologue: stage tile 0 into buffer 0 (no drain — first iteration's vmcnt handles it)
#pragma unroll
    for (int i = 0; i < 2; ++i)
        __builtin_amdgcn_global_load_lds((gas_t)(ga[i]), (las_t)(&As[0][0] + loffA[i]), 16, 0, 0);
#pragma unroll
    for (int i = 0; i < 4; ++i)
        __builtin_amdgcn_global_load_lds((gas_t)(gb[i]), (las_t)(&Bs[0][0] + loffB[i]), 16, 0, 0);

    for (int t = 0; t < nt; ++t) {
        int cur = t & 1;
        if (t + 1 < nt) {
            int k0 = (t + 1) << 5;
            int nxt = cur ^ 1;
#pragma unroll
            for (int i = 0; i < 2; ++i)
                __builtin_amdgcn_global_load_lds((gas_t)(ga[i] + k0), (las_t)(&As[nxt][0] + loffA[i]), 16, 0, 0);
#pragma unroll
            for (int i = 0; i < 4; ++i)
                __builtin_amdgcn_global_load_lds((gas_t)(gb[i] + k0), (las_t)(&Bs[nxt][0] + loffB[i]), 16, 0, 0);
            // drain only tile t's 6 loads; keep tile t+1's 6 in flight across the barrier
            asm volatile("s_waitcnt vmcnt(6)" ::: "memory");
        } else {
            asm volatile("s_waitcnt vmcnt(0)" ::: "memory");
        }
        __builtin_amdgcn_s_barrier();   // everyone's tile-t loads landed
        bf16x8 af[4], bfr[8];
#pragma unroll
        for (int i = 0; i < 4; ++i)
            af[i]  = *(const bf16x8*)(&As[cur][0] + offA[i]);
#pragma unroll
        for (int i = 0; i < 8; ++i)
            bfr[i] = *(const bf16x8*)(&Bs[cur][0] + offB[i]);
#pragma unroll
        for (int i = 0; i < 4; ++i)
#pragma unroll
            for (int j = 0; j < 8; ++j)
                acc[i][j] = __builtin_amdgcn_mfma_f32_16x16x32_bf16(af[i], bfr[j], acc[i][j], 0, 0, 0);
        if (t + 1 < nt) {
            // all waves' reads of buf[cur] complete before it can be overwritten next iter
            asm volatile("s_waitcnt lgkmcnt(0)" ::: "memory");
            __builtin_amdgcn_s_barrier();
        }
    }

    float* Cf = (float*)Cv;
    __hip_bfloat16* Cb = (__hip_bfloat16*)Cv;
    if (ctrans == 2) {
        // col-decomposed transposed store: fast axis (lrow lanes) is contiguous in memory
        long long cb2[8]; int cols[8];
#pragma unroll
        for (int ni = 0; ni < 8; ++ni) {
            int col = n0 + wn + ni * 16 + lrow;
            cols[ni] = col;
            int qq = col / cSub, sl = col - qq * cSub;
            cb2[ni] = cbase + (long long)qq * cOuter + sl;
        }
#pragma unroll
        for (int mi = 0; mi < 4; ++mi) {
#pragma unroll
            for (int rr = 0; rr < 4; ++rr) {
                int row = m0 + wm + mi * 16 + quad * 4 + rr;
                if (row >= Mlim) continue;
                float bv = bias ? bias[row] : 0.f;
                long long rb = (long long)row * ldc;
#pragma unroll
                for (int ni = 0; ni < 8; ++ni) {
                    if (cols[ni] < Nlim) {
                        float v = acc[mi][ni][rr] + bv;
                        if (act == 1) v = gelu_f(v);
                        long long off = cb2[ni] + rb;
                        if (out_bf16) Cb[off] = __float2bfloat16(v);
                        else          Cf[off] = v;
                    }
                }
            }
        }
    } else {
#pragma unroll
        for (int mi = 0; mi < 4; ++mi) {
#pragma unroll
            for (int rr = 0; rr < 4; ++rr) {
                int row = m0 + wm + mi * 16 + quad * 4 + rr;
                if (row >= Mlim) continue;
                int qq = row / cSub;
                int sl = row - qq * cSub;
                long long rb = ctrans ? (cbase + (long long)qq * cOuter + sl)
                                      : (cbase + ((long long)qq * cOuter + sl) * ldc);
#pragma unroll
                for (int ni = 0; ni < 8; ++ni) {
                    int col = n0 + wn + ni * 16 + lrow;
                    if (col < Nlim) {
                        float v = acc[mi][ni][rr];
                        if (bias) v += bias[col];
                        if (act == 1) v = gelu_f(v);
                        long long off = ctrans ? (rb + (long long)col * ldc) : (rb + col);
                        if (out_bf16) Cb[off] = __float2bfloat16(v);
                        else          Cf[off] = v;
                    }
                }
            }
        }
    }
}

static inline void mfma2(hipStream_t st, int nx, int ny, int nz, int order,
                         const void* A, long long aBS, int lda, int Mrows,
                         const void* Bt, long long bBS, int ldb, int Nrows,
                         const float* bias, long long biasBS,
                         void* C, long long cBS, int ldc, int cSub, long long cOuter,
                         int Mlim, int Nlim, int K, int act, int obf, int ct) {
    mfma2_k<<<nx * ny * nz, dim3(256), 0, st>>>((const __hip_bfloat16*)A, aBS, lda, Mrows,
                                        (const __hip_bfloat16*)Bt, bBS, ldb, Nrows,
                                        bias, biasBS, C, cBS, ldc, cSub, cOuter,
                                        Mlim, Nlim, K, act, obf, ct, nx, ny, order);
}

// ---------------- launcher ----------------
extern "C" void kernel_launch(void* const* d_in, const int* in_sizes, int n_in,
                              void* d_out, int out_size, void* d_ws, size_t ws_size,
                              hipStream_t stream) {
    const float* x     = (const float*)d_in[0];
    const float* aw    = (const float*)d_in[1];
    const float* gamma = (const float*)d_in[2];
    const float* beta  = (const float*)d_in[3];
    const float* vsg_w = (const float*)d_in[4];
    const float* vsg_b = (const float*)d_in[5];
    const float* mu    = (const float*)d_in[6];
    const float* scale = (const float*)d_in[7];
    const float* w1    = (const float*)d_in[8];
    const float* b1    = (const float*)d_in[9];
    const float* w2    = (const float*)d_in[10];
    const float* b2    = (const float*)d_in[11];
    const float* cw1   = (const float*)d_in[12];
    const float* cb1   = (const float*)d_in[13];
    const float* cw2   = (const float*)d_in[14];
    const float* cb2   = (const float*)d_in[15];
    float* out = (float*)d_out;

    float* ws = (float*)d_ws;

    // ---- workspace (units: float). region1 = [img_n | logits], later h aliases it. ----
    const long long IMGN_FL = (long long)NTOK * DIM / 2;           // 12,582,912
    const long long LOG_FL  = (long long)NTOK * ESL;               //  4,325,376
    const long long REG1_FL = (long long)NE * NB * NS * NH / 2;    // 17,301,504 (h)
    __hip_bfloat16* img_n = (__hip_bfloat16*)ws;
    float* logits = ws + IMGN_FL;
    __hip_bfloat16* h = (__hip_bfloat16*)ws;                       // alias region1
    long long o = REG1_FL;
    __hip_bfloat16* dT16    = (__hip_bfloat16*)(ws + o); o += (long long)NB * ESL * NIMG / 2;   // 2,162,688
    __hip_bfloat16* comb_p  = (__hip_bfloat16*)(ws + o); o += (long long)NTOK * KPAD / 2;       // 2,621,440
    // region2 = imgT (then slot_outT overwrites it; sized for the larger)
    __hip_bfloat16* imgT    = (__hip_bfloat16*)(ws + o);
    __hip_bfloat16* slot_outT = imgT;                    o += (long long)NB * DIM * KPAD / 2;   // 15,728,640
    __hip_bfloat16* slot_in = (__hip_bfloat16*)(ws + o); o += (long long)NE * NB * NS * DIM / 2;// 12,976,128
    __hip_bfloat16* mu_p    = (__hip_bfloat16*)(ws + o); o += 256 * DIM / 2;
    float* slot_bias = ws + o;                           o += NB * DIM;
    float* t2        = ws + o;                           o += NTOK;
    __hip_bfloat16* w1t  = (__hip_bfloat16*)(ws + o);    o += (long long)NE * NH * DIM / 2;
    __hip_bfloat16* w2t  = (__hip_bfloat16*)(ws + o);    o += (long long)NE * DIM * NH / 2;
    __hip_bfloat16* cw1t = (__hip_bfloat16*)(ws + o);    o += (long long)4 * DIM * DIM / 2;
    __hip_bfloat16* cw2t = (__hip_bfloat16*)(ws + o);    o += (long long)4 * DIM * DIM / 2;
    __hip_bfloat16* cls16 = (__hip_bfloat16*)(ws + o);   o += NB * DIM / 2;
    __hip_bfloat16* cls_h = (__hip_bfloat16*)(ws + o);   o += (long long)NB * 4 * DIM / 2;

    // ---- prep (every call; graph-safe) ----
    repack_mu_k<<<(256 * DIM + 255) / 256, 256, 0, stream>>>(mu, mu_p);
    transpose_bf16_k<<<dim3(NH / 32, DIM / 32, NE), dim3(32, 8), 0, stream>>>(w1, w1t, DIM, NH, (long long)DIM * NH, (long long)NH * DIM);
    transpose_bf16_k<<<dim3(DIM / 32, NH / 32, NE), dim3(32, 8), 0, stream>>>(w2, w2t, NH, DIM, (long long)NH * DIM, (long long)DIM * NH);
    transpose_bf16_k<<<dim3(4 * DIM / 32, DIM / 32, 1), dim3(32, 8), 0, stream>>>(cw1, cw1t, DIM, 4 * DIM, 0, 0);
    transpose_bf16_k<<<dim3(DIM / 32, 4 * DIM / 32, 1), dim3(32, 8), 0, stream>>>(cw2, cw2t, 4 * DIM, DIM, 0, 0);
    cls_bf16_k<<<(NB * DIM + 255) / 256, 256, 0, stream>>>(x, cls16);
    // imgT[b] (768 x 128) = img[b]^T
    transpose_bf16_k<<<dim3(DIM / 32, NIMG / 32, NB), dim3(32, 8), 0, stream>>>(x + DIM, imgT, NIMG, DIM, (long long)129 * DIM, (long long)DIM * NIMG);

    // ---- scalar path ----
    slot_bias_k<<<NB, 256, 0, stream>>>(x, aw, vsg_w, vsg_b, slot_bias);
    ln_t2_k<<<NTOK, 256, 0, stream>>>(x, gamma, beta, slot_bias, img_n, t2);

    // t1 = img_n @ mu_p^T : (32768x768) x (256x768)^T -> logits fp32 (ldc=132)
    mfma2(stream, 1, NTOK / 128, 1, 0,
          img_n, 0, DIM, NTOK, mu_p, 0, DIM, 256, nullptr, 0,
          logits, 0, ESL, BIGI, 0, NTOK, ESL, DIM, 0, 0, 0);

    mask_k<<<(NTOK * ESL + 255) / 256, 256, 0, stream>>>(logits, t2, aw, scale);
    dispatch_k<<<dim3(ESL, NB), 128, 0, stream>>>(logits, dT16);
    combine_k<<<NTOK, 64, 0, stream>>>(logits, comb_p);

    // slot_in(e, b*44+s, d) bf16 = dT16[b](132x128) @ imgT[b]^T ; M=132 (clamped), batch=NB
    mfma2(stream, DIM / 256, 2, NB, 0,
          dT16, (long long)ESL * NIMG, NIMG, ESL,
          imgT, (long long)DIM * NIMG, NIMG, DIM, nullptr, 0,
          slot_in, (long long)NS * DIM, DIM, NS, NB * NS,
          ESL, DIM, NIMG, 0, 1, 0);

    // h(e) = gelu(slot_in(e) @ w1t(e)^T + b1(e)) : M=11264, N=1024, K=768
    // order 0: x-blocks sharing an A(slot_in)-panel are consecutive -> same XCD L2
    mfma2(stream, NH / 256, NB * NS / 128, NE, 0,
          slot_in, (long long)NB * NS * DIM, DIM, NB * NS,
          w1t, (long long)NH * DIM, DIM, NH, b1, NH,
          h, (long long)NB * NS * NH, NH, BIGI, 0,
          NB * NS, NH, DIM, 1, 1, 0);

    // zero K-pad cols [132,160) of slot_outT (imgT dead now; safe before slot_out GEMM)
    zero_pad_k<<<(NB * DIM * (KPAD - ESL) + 255) / 256, 256, 0, stream>>>(slot_outT);

    // slot_outT[b](768 x 160) bf16 computed DIRECTLY transposed:
    // C(row=d, col=b*44+s) = w2t(e) @ h(e)^T + b2(e)[d]
    // order 1: the 6 y-blocks sharing a B(h)-panel are consecutive -> same XCD L2
    mfma2(stream, NB * NS / 256, DIM / 128, NE, 1,
          w2t, (long long)DIM * NH, NH, DIM,
          h, (long long)NB * NS * NH, NH, NB * NS,
          b2, DIM,
          slot_outT, NS, KPAD, NS, (long long)DIM * KPAD,
          DIM, NB * NS, NH, 0, 1, 2);

    // img_out[b](128x768) = comb_p[b](128x160) @ slot_outT[b](768x160)^T -> out rows b*129+1+n
    mfma2(stream, DIM / 256, 1, NB, 0,
          comb_p, (long long)NIMG * KPAD, KPAD, NIMG,
          slot_outT, (long long)DIM * KPAD, KPAD, DIM, nullptr, 0,
          out + DIM, (long long)129 * DIM, DIM, BIGI, 0,
          NIMG, DIM, KPAD, 0, 0, 0);

    // cls path: cls_h = gelu(cls16 @ cw1t^T + cb1) ; cls_out -> out rows b*129
    mfma2(stream, 4 * DIM / 256, NB / 128, 1, 0,
          cls16, 0, DIM, NB, cw1t, 0, DIM, 4 * DIM, cb1, 0,
          cls_h, 0, 4 * DIM, BIGI, 0, NB, 4 * DIM, DIM, 1, 1, 0);
    mfma2(stream, DIM / 256, NB / 128, 1, 0,
          cls_h, 0, 4 * DIM, NB, cw2t, 0, 4 * DIM, DIM, cb2, 0,
          out, 0, DIM, 1, 129, NB, DIM, 4 * DIM, 0, 0, 0);
}

// Round 6
// 898.534 us; speedup vs baseline: 1.2453x; 1.2453x over previous
//
#include <hip/hip_runtime.h>
#include <hip/hip_bf16.h>
#include <math.h>

#define NB   256
#define NIMG 128
#define DIM  768
#define NE   3
#define NS   44
#define NH   1024
#define ESL  132          // NE*NS
#define NTOK (NB*NIMG)    // 32768
#define MAXSLOTS 88
#define BIGI (1 << 30)
#define KPAD 160          // combine K padded to mult of 32

typedef __bf16 bf16x8 __attribute__((ext_vector_type(8)));
typedef float f32x4 __attribute__((ext_vector_type(4)));
typedef const __attribute__((address_space(1))) void* gas_t;
typedef __attribute__((address_space(3))) void* las_t;

// ---------------- helpers ----------------
__device__ __forceinline__ float gelu_f(float v) {
    return 0.5f * v * (1.0f + erff(v * 0.70710678118654752f));
}

__device__ __forceinline__ float block_reduce_sum256(float v, float* red) {
    int tid = threadIdx.x;
    red[tid] = v;
    __syncthreads();
    for (int s = 128; s > 0; s >>= 1) {
        if (tid < s) red[tid] += red[tid + s];
        __syncthreads();
    }
    float r = red[0];
    __syncthreads();
    return r;
}

// ---------------- repack mu: (e,d,88) -> Bt[r=e*44+s][d], bf16, padded to 256 rows ----------------
__global__ void repack_mu_k(const float* __restrict__ mu, __hip_bfloat16* __restrict__ bt) {
    int idx = blockIdx.x * 256 + threadIdx.x;
    if (idx >= 256 * DIM) return;
    int r = idx / DIM, d = idx - r * DIM;
    float v = 0.f;
    if (r < ESL) {
        int e = r / NS, s = r - e * NS;
        v = mu[((size_t)e * DIM + d) * MAXSLOTS + s];
    }
    bt[idx] = __float2bfloat16(v);
}

// ---------------- fp32 (R x Cc) -> bf16 (Cc x R) transpose, batched, general strides ----------------
__global__ void transpose_bf16_k(const float* __restrict__ in, __hip_bfloat16* __restrict__ outp,
                                 int R, int Cc, long long inBS, long long outBS) {
    __shared__ float t[32][33];
    in   += (long long)blockIdx.z * inBS;
    outp += (long long)blockIdx.z * outBS;
    int c0 = blockIdx.x * 32, r0 = blockIdx.y * 32;
    int tx = threadIdx.x, ty = threadIdx.y;   // 32 x 8
    for (int i = 0; i < 32; i += 8) {
        int r = r0 + ty + i, c = c0 + tx;
        t[ty + i][tx] = (r < R && c < Cc) ? in[(size_t)r * Cc + c] : 0.f;
    }
    __syncthreads();
    for (int i = 0; i < 32; i += 8) {
        int r = c0 + ty + i, c = r0 + tx;     // out is Cc x R
        if (r < Cc && c < R) outp[(size_t)r * R + c] = __float2bfloat16(t[tx][ty + i]);
    }
}

// ---------------- cls rows -> bf16 copy ----------------
__global__ void cls_bf16_k(const float* __restrict__ x, __hip_bfloat16* __restrict__ cls16) {
    int idx = blockIdx.x * 256 + threadIdx.x;
    if (idx >= NB * DIM) return;
    int b = idx / DIM, j = idx - b * DIM;
    cls16[idx] = __float2bfloat16(x[(size_t)b * 129 * DIM + j]);
}

// ---------------- zero the K-pad cols [ESL, KPAD) of slot_outT [b][d][KPAD] ----------------
__global__ void zero_pad_k(__hip_bfloat16* __restrict__ p) {
    const int per = KPAD - ESL;                 // 28
    const int total = NB * DIM * per;           // 5,505,024
    int idx = blockIdx.x * 256 + threadIdx.x;
    if (idx >= total) return;
    int bd = idx / per, k = idx - bd * per;
    p[(size_t)bd * KPAD + ESL + k] = __float2bfloat16(0.f);
}

// ---------------- slot_bias[b,:] = cls@vsg_w[:768] + af*vsg_w[768] + vsg_b ----------------
__global__ void slot_bias_k(const float* __restrict__ x, const float* __restrict__ aw,
                            const float* __restrict__ vsg_w, const float* __restrict__ vsg_b,
                            float* __restrict__ slot_bias) {
    __shared__ float red[256];
    __shared__ float cls[DIM];
    int b = blockIdx.x, tid = threadIdx.x;
    float a = (tid < NIMG) ? aw[b * NIMG + tid] : 0.f;
    float af = block_reduce_sum256(a, red) * (1.0f / NIMG);
    for (int j = tid; j < DIM; j += 256) cls[j] = x[(size_t)b * 129 * DIM + j];
    __syncthreads();
    int j0 = tid, j1 = tid + 256, j2 = tid + 512;
    float acc0 = 0.f, acc1 = 0.f, acc2 = 0.f;
    for (int d = 0; d < DIM; ++d) {
        float c = cls[d];
        const float* wr = vsg_w + (size_t)d * DIM;
        acc0 = fmaf(c, wr[j0], acc0);
        acc1 = fmaf(c, wr[j1], acc1);
        acc2 = fmaf(c, wr[j2], acc2);
    }
    const float* wl = vsg_w + (size_t)DIM * DIM;
    float* out = slot_bias + (size_t)b * DIM;
    out[j0] = acc0 + vsg_b[j0] + af * wl[j0];
    out[j1] = acc1 + vsg_b[j1] + af * wl[j1];
    out[j2] = acc2 + vsg_b[j2] + af * wl[j2];
}

// ---------------- LayerNorm (bf16 out) + t2 = dot(img_n, slot_bias[b]) ----------------
__global__ void ln_t2_k(const float* __restrict__ x, const float* __restrict__ gamma,
                        const float* __restrict__ beta, const float* __restrict__ slot_bias,
                        __hip_bfloat16* __restrict__ img_n, float* __restrict__ t2) {
    __shared__ float red[256];
    int tok = blockIdx.x;
    int b = tok >> 7, n = tok & 127;
    int tid = threadIdx.x;
    const float* row = x + ((size_t)b * 129 + 1 + n) * DIM;
    float v0 = row[tid], v1 = row[tid + 256], v2 = row[tid + 512];
    float s  = block_reduce_sum256(v0 + v1 + v2, red);
    float ss = block_reduce_sum256(v0*v0 + v1*v1 + v2*v2, red);
    float mean = s * (1.0f / DIM);
    float var  = ss * (1.0f / DIM) - mean * mean;
    float inv  = rsqrtf(var + 1e-5f);
    const float* sb = slot_bias + (size_t)b * DIM;
    __hip_bfloat16* orow = img_n + (size_t)tok * DIM;
    float tacc = 0.f;
    int j = tid;
    float y0 = (v0 - mean) * inv * gamma[j] + beta[j]; orow[j] = __float2bfloat16(y0); tacc = fmaf(y0, sb[j], tacc);
    j = tid + 256;
    float y1 = (v1 - mean) * inv * gamma[j] + beta[j]; orow[j] = __float2bfloat16(y1); tacc = fmaf(y1, sb[j], tacc);
    j = tid + 512;
    float y2 = (v2 - mean) * inv * gamma[j] + beta[j]; orow[j] = __float2bfloat16(y2); tacc = fmaf(y2, sb[j], tacc);
    float t = block_reduce_sum256(tacc, red);
    if (tid == 0) t2[tok] = t;
}

// ---------------- FUSED mask + combine + dispatch, one block per batch b ----------------
// Ls[n][r] = masked logit = (e==sel(aw)) ? scale*(t1+t2) : 0   (128 x 132, +1 pad col)
// combine: softmax over r per token row -> comb_p[tok][0..159] (zero K-pad)
// dispatch: softmax over n per column  -> dT16[(b*ESL+es)*NIMG + n]
__global__ __launch_bounds__(256)
void softmax_fused_k(const float* __restrict__ L, const float* __restrict__ t2,
                     const float* __restrict__ aw, const float* __restrict__ scale,
                     __hip_bfloat16* __restrict__ dT16, __hip_bfloat16* __restrict__ C) {
    __shared__ float Ls[NIMG][ESL + 1];   // 128 x 133 fp32 = 68 KB, conflict-free both axes
    __shared__ float awS[NIMG], t2S[NIMG];
    int b = blockIdx.x, tid = threadIdx.x;
    if (tid < NIMG) { awS[tid] = aw[b * NIMG + tid]; t2S[tid] = t2[b * NIMG + tid]; }
    __syncthreads();
    float sc = scale[0];
    const float* Lb = L + (size_t)b * NIMG * ESL;
    for (int i = tid; i < NIMG * ESL; i += 256) {
        int n = i / ESL, r = i - n * ESL;
        int e = r / NS;
        float a = awS[n];
        int sel = (a > 0.7f) ? 0 : ((a >= 0.3f) ? 1 : 2);
        Ls[n][r] = (e == sel) ? sc * (Lb[i] + t2S[n]) : 0.f;
    }
    __syncthreads();
    // combine (reads Ls, does not modify)
    if (tid < NIMG) {
        int n = tid;
        float m = -1e30f;
        for (int r = 0; r < ESL; ++r) m = fmaxf(m, Ls[n][r]);
        float s = 0.f;
        for (int r = 0; r < ESL; ++r) s += __expf(Ls[n][r] - m);
        float inv = 1.0f / s;
        __hip_bfloat16* orow = C + ((size_t)b * NIMG + n) * KPAD;
        for (int r = 0; r < ESL; ++r) orow[r] = __float2bfloat16(__expf(Ls[n][r] - m) * inv);
        for (int r = ESL; r < KPAD; ++r) orow[r] = __float2bfloat16(0.f);
    }
    __syncthreads();   // combine reads done before dispatch overwrites Ls
    // dispatch (overwrites Ls cells with exp values)
    if (tid < ESL) {
        int es = tid;
        float m = -1e30f;
        for (int n = 0; n < NIMG; ++n) m = fmaxf(m, Ls[n][es]);
        float s = 0.f;
        for (int n = 0; n < NIMG; ++n) { float e = __expf(Ls[n][es] - m); Ls[n][es] = e; s += e; }
        float inv = 1.0f / s;
        __hip_bfloat16* orow = dT16 + ((size_t)b * ESL + es) * NIMG;
        for (int n = 0; n < NIMG; ++n) orow[n] = __float2bfloat16(Ls[n][es] * inv);
    }
}

// ---------------- bf16 MFMA GEMM v7: TRIPLE-buffered async staging, 1 barrier/iter, XCD swizzle ----------------
// C = act(A @ Bt^T + bias). A: Mrows x lda bf16; Bt: Nrows x ldb bf16. 128x128 tile, 4 waves 2x2.
// Per-iter: STAGE(t+1 -> buf[(t+1)%3]); vmcnt(4) [drain tile t only]; barrier; ds_read buf[t%3]; MFMA;
//           lgkmcnt(0).
// Safety: buffer b=t%3 read at iter t is next overwritten by staging issued at iter t+2 top,
// which is after barrier(t+1); every wave passes barrier(t+1) only after its trailing lgkmcnt(0)
// (reads landed in VGPRs). Each wave's vmcnt(4) precedes the barrier, so at barrier-exit ALL
// waves' tile-t loads have landed.
// Grid 1D, bijective XCD-chunk swizzle (m204). order=0: x fastest; order=1: y fastest.
// ctrans=0 (normal):   off = z*cBS + ((row/cSub)*cOuter + row%cSub)*ldc + col ; bias[col]
// ctrans=1 (row-T):    off = z*cBS + (row/cSub)*cOuter + row%cSub + col*ldc  ; bias[col]
// ctrans=2 (col-T):    off = z*cBS + (col/cSub)*cOuter + col%cSub + row*ldc  ; bias[row]
__global__ __launch_bounds__(256)
void mfma2_k(const __hip_bfloat16* __restrict__ A_, long long aBS, int lda, int Mrows,
             const __hip_bfloat16* __restrict__ Bt_, long long bBS, int ldb, int Nrows,
             const float* __restrict__ bias, long long biasBS,
             void* __restrict__ Cv, long long cBS, int ldc, int cSub, long long cOuter,
             int Mlim, int Nlim, int K, int act, int out_bf16, int ctrans,
             int nx, int ny, int order)
{
    // ---- bijective XCD-chunk swizzle ----
    int nwg = gridDim.x;
    int hw = blockIdx.x;
    int q = nwg >> 3, r = nwg & 7;
    int xcd = hw & 7, off0 = hw >> 3;
    int wid = (xcd < r ? xcd * (q + 1) : r * (q + 1) + (xcd - r) * q) + off0;
    int pp = nx * ny;
    int bz = wid / pp;
    int rm = wid - bz * pp;
    int bx, by;
    if (order == 0) { by = rm / nx; bx = rm - by * nx; }
    else            { bx = rm / ny; by = rm - bx * ny; }

    const unsigned short* A  = (const unsigned short*)A_  + (long long)bz * aBS;
    const unsigned short* Bt = (const unsigned short*)Bt_ + (long long)bz * bBS;
    if (bias) bias += (long long)bz * biasBS;
    long long cbase = (long long)bz * cBS;

    __shared__ unsigned short As[3][128 * 32];   // 3 x 8 KB
    __shared__ unsigned short Bs[3][128 * 32];   // 3 x 8 KB  (48 KB total)

    int tid = threadIdx.x;
    int lane = tid & 63, wv = tid >> 6;
    int m0 = by * 128, n0 = bx * 128;

    // staging: wave wv issues lds-load instrs j = 2wv, 2wv+1 for A and B.
    // instr j covers LDS bytes [j*1024, j*1024+1024): lane l -> offset j*1024 + l*16.
    // position p = j*64+l -> tile row r = p>>2, LDS chunk cl = p&3,
    // global chunk cg = cl ^ ((r>>1)&3)   (swizzle; makes frag ds_read_b128 2-way max)
    const unsigned short* ga[2];
    const unsigned short* gb[2];
    int ldsoff[2];
#pragma unroll
    for (int i = 0; i < 2; ++i) {
        int j = wv * 2 + i;
        int p = j * 64 + lane;
        int rr = p >> 2;
        int cg = (p & 3) ^ ((rr >> 1) & 3);
        int ra = m0 + rr; if (ra > Mrows - 1) ra = Mrows - 1;
        int rb = n0 + rr; if (rb > Nrows - 1) rb = Nrows - 1;
        ga[i] = A  + (long long)ra * lda + cg * 8;
        gb[i] = Bt + (long long)rb * ldb + cg * 8;
        ldsoff[i] = j * 512;
    }

    int lrow = lane & 15, quad = lane >> 4;
    int wm = (wv >> 1) * 64, wn = (wv & 1) * 64;
    int offA[4], offB[4];
#pragma unroll
    for (int i = 0; i < 4; ++i) {
        int rowa = wm + i * 16 + lrow;
        offA[i] = rowa * 32 + ((quad ^ ((rowa >> 1) & 3)) * 8);
        int rowb = wn + i * 16 + lrow;
        offB[i] = rowb * 32 + ((quad ^ ((rowb >> 1) & 3)) * 8);
    }

    f32x4 acc[4][4] = {};
    int nt = K >> 5;

    // prologue: stage tile 0 into buffer 0
#pragma unroll
    for (int i = 0; i < 2; ++i) {
        __builtin_amdgcn_global_load_lds((gas_t)(ga[i]), (las_t)(&As[0][0] + ldsoff[i]), 16, 0, 0);
        __builtin_amdgcn_global_load_lds((gas_t)(gb[i]), (las_t)(&Bs[0][0] + ldsoff[i]), 16, 0, 0);
    }

    int cur = 0;
    for (int t = 0; t < nt; ++t) {
        int nxt = (cur == 2) ? 0 : cur + 1;
        if (t + 1 < nt) {
            int k0 = (t + 1) << 5;
#pragma unroll
            for (int i = 0; i < 2; ++i) {
                __builtin_amdgcn_global_load_lds((gas_t)(ga[i] + k0), (las_t)(&As[nxt][0] + ldsoff[i]), 16, 0, 0);
                __builtin_amdgcn_global_load_lds((gas_t)(gb[i] + k0), (las_t)(&Bs[nxt][0] + ldsoff[i]), 16, 0, 0);
            }
            // drain only tile t's 4 loads; tile t+1's 4 stay in flight across the barrier
            asm volatile("s_waitcnt vmcnt(4)" ::: "memory");
        } else {
            asm volatile("s_waitcnt vmcnt(0)" ::: "memory");
        }
        __builtin_amdgcn_s_barrier();   // all waves' tile-t loads landed
        bf16x8 af[4], bfr[4];
#pragma unroll
        for (int i = 0; i < 4; ++i) {
            af[i]  = *(const bf16x8*)(&As[cur][0] + offA[i]);
            bfr[i] = *(const bf16x8*)(&Bs[cur][0] + offB[i]);
        }
#pragma unroll
        for (int i = 0; i < 4; ++i)
#pragma unroll
            for (int j = 0; j < 4; ++j)
                acc[i][j] = __builtin_amdgcn_mfma_f32_16x16x32_bf16(af[i], bfr[j], acc[i][j], 0, 0, 0);
        // pin: this wave's ds_reads complete before it can reach the next barrier
        asm volatile("s_waitcnt lgkmcnt(0)" ::: "memory");
        cur = nxt;
    }

    float* Cf = (float*)Cv;
    __hip_bfloat16* Cb = (__hip_bfloat16*)Cv;
    if (ctrans == 2) {
        // col-decomposed transposed store: fast axis (lrow lanes) is contiguous in memory
        long long cb2[4]; int cols[4];
#pragma unroll
        for (int ni = 0; ni < 4; ++ni) {
            int col = n0 + wn + ni * 16 + lrow;
            cols[ni] = col;
            int qq = col / cSub, sl = col - qq * cSub;
            cb2[ni] = cbase + (long long)qq * cOuter + sl;
        }
#pragma unroll
        for (int mi = 0; mi < 4; ++mi) {
#pragma unroll
            for (int rr = 0; rr < 4; ++rr) {
                int row = m0 + wm + mi * 16 + quad * 4 + rr;
                if (row >= Mlim) continue;
                float bv = bias ? bias[row] : 0.f;
                long long rb = (long long)row * ldc;
#pragma unroll
                for (int ni = 0; ni < 4; ++ni) {
                    if (cols[ni] < Nlim) {
                        float v = acc[mi][ni][rr] + bv;
                        if (act == 1) v = gelu_f(v);
                        long long off = cb2[ni] + rb;
                        if (out_bf16) Cb[off] = __float2bfloat16(v);
                        else          Cf[off] = v;
                    }
                }
            }
        }
    } else {
#pragma unroll
        for (int mi = 0; mi < 4; ++mi) {
#pragma unroll
            for (int rr = 0; rr < 4; ++rr) {
                int row = m0 + wm + mi * 16 + quad * 4 + rr;
                if (row >= Mlim) continue;
                int qq = row / cSub;
                int sl = row - qq * cSub;
                long long rb = ctrans ? (cbase + (long long)qq * cOuter + sl)
                                      : (cbase + ((long long)qq * cOuter + sl) * ldc);
#pragma unroll
                for (int ni = 0; ni < 4; ++ni) {
                    int col = n0 + wn + ni * 16 + lrow;
                    if (col < Nlim) {
                        float v = acc[mi][ni][rr];
                        if (bias) v += bias[col];
                        if (act == 1) v = gelu_f(v);
                        long long off = ctrans ? (rb + (long long)col * ldc) : (rb + col);
                        if (out_bf16) Cb[off] = __float2bfloat16(v);
                        else          Cf[off] = v;
                    }
                }
            }
        }
    }
}

static inline void mfma2(hipStream_t st, int nx, int ny, int nz, int order,
                         const void* A, long long aBS, int lda, int Mrows,
                         const void* Bt, long long bBS, int ldb, int Nrows,
                         const float* bias, long long biasBS,
                         void* C, long long cBS, int ldc, int cSub, long long cOuter,
                         int Mlim, int Nlim, int K, int act, int obf, int ct) {
    mfma2_k<<<nx * ny * nz, dim3(256), 0, st>>>((const __hip_bfloat16*)A, aBS, lda, Mrows,
                                        (const __hip_bfloat16*)Bt, bBS, ldb, Nrows,
                                        bias, biasBS, C, cBS, ldc, cSub, cOuter,
                                        Mlim, Nlim, K, act, obf, ct, nx, ny, order);
}

// ---------------- launcher ----------------
extern "C" void kernel_launch(void* const* d_in, const int* in_sizes, int n_in,
                              void* d_out, int out_size, void* d_ws, size_t ws_size,
                              hipStream_t stream) {
    const float* x     = (const float*)d_in[0];
    const float* aw    = (const float*)d_in[1];
    const float* gamma = (const float*)d_in[2];
    const float* beta  = (const float*)d_in[3];
    const float* vsg_w = (const float*)d_in[4];
    const float* vsg_b = (const float*)d_in[5];
    const float* mu    = (const float*)d_in[6];
    const float* scale = (const float*)d_in[7];
    const float* w1    = (const float*)d_in[8];
    const float* b1    = (const float*)d_in[9];
    const float* w2    = (const float*)d_in[10];
    const float* b2    = (const float*)d_in[11];
    const float* cw1   = (const float*)d_in[12];
    const float* cb1   = (const float*)d_in[13];
    const float* cw2   = (const float*)d_in[14];
    const float* cb2   = (const float*)d_in[15];
    float* out = (float*)d_out;

    float* ws = (float*)d_ws;

    // ---- workspace (units: float). region1 = [img_n | logits], later h aliases it. ----
    const long long IMGN_FL = (long long)NTOK * DIM / 2;           // 12,582,912
    const long long REG1_FL = (long long)NE * NB * NS * NH / 2;    // 17,301,504 (h)
    __hip_bfloat16* img_n = (__hip_bfloat16*)ws;
    float* logits = ws + IMGN_FL;
    __hip_bfloat16* h = (__hip_bfloat16*)ws;                       // alias region1
    long long o = REG1_FL;
    __hip_bfloat16* dT16    = (__hip_bfloat16*)(ws + o); o += (long long)NB * ESL * NIMG / 2;   // 2,162,688
    __hip_bfloat16* comb_p  = (__hip_bfloat16*)(ws + o); o += (long long)NTOK * KPAD / 2;       // 2,621,440
    // region2 = imgT (then slot_outT overwrites it; sized for the larger)
    __hip_bfloat16* imgT    = (__hip_bfloat16*)(ws + o);
    __hip_bfloat16* slot_outT = imgT;                    o += (long long)NB * DIM * KPAD / 2;   // 15,728,640
    __hip_bfloat16* slot_in = (__hip_bfloat16*)(ws + o); o += (long long)NE * NB * NS * DIM / 2;// 12,976,128
    __hip_bfloat16* mu_p    = (__hip_bfloat16*)(ws + o); o += 256 * DIM / 2;
    float* slot_bias = ws + o;                           o += NB * DIM;
    float* t2        = ws + o;                           o += NTOK;
    __hip_bfloat16* w1t  = (__hip_bfloat16*)(ws + o);    o += (long long)NE * NH * DIM / 2;
    __hip_bfloat16* w2t  = (__hip_bfloat16*)(ws + o);    o += (long long)NE * DIM * NH / 2;
    __hip_bfloat16* cw1t = (__hip_bfloat16*)(ws + o);    o += (long long)4 * DIM * DIM / 2;
    __hip_bfloat16* cw2t = (__hip_bfloat16*)(ws + o);    o += (long long)4 * DIM * DIM / 2;
    __hip_bfloat16* cls16 = (__hip_bfloat16*)(ws + o);   o += NB * DIM / 2;
    __hip_bfloat16* cls_h = (__hip_bfloat16*)(ws + o);   o += (long long)NB * 4 * DIM / 2;

    // ---- prep (every call; graph-safe) ----
    repack_mu_k<<<(256 * DIM + 255) / 256, 256, 0, stream>>>(mu, mu_p);
    transpose_bf16_k<<<dim3(NH / 32, DIM / 32, NE), dim3(32, 8), 0, stream>>>(w1, w1t, DIM, NH, (long long)DIM * NH, (long long)NH * DIM);
    transpose_bf16_k<<<dim3(DIM / 32, NH / 32, NE), dim3(32, 8), 0, stream>>>(w2, w2t, NH, DIM, (long long)NH * DIM, (long long)DIM * NH);
    transpose_bf16_k<<<dim3(4 * DIM / 32, DIM / 32, 1), dim3(32, 8), 0, stream>>>(cw1, cw1t, DIM, 4 * DIM, 0, 0);
    transpose_bf16_k<<<dim3(DIM / 32, 4 * DIM / 32, 1), dim3(32, 8), 0, stream>>>(cw2, cw2t, 4 * DIM, DIM, 0, 0);
    cls_bf16_k<<<(NB * DIM + 255) / 256, 256, 0, stream>>>(x, cls16);
    // imgT[b] (768 x 128) = img[b]^T
    transpose_bf16_k<<<dim3(DIM / 32, NIMG / 32, NB), dim3(32, 8), 0, stream>>>(x + DIM, imgT, NIMG, DIM, (long long)129 * DIM, (long long)DIM * NIMG);

    // ---- scalar path ----
    slot_bias_k<<<NB, 256, 0, stream>>>(x, aw, vsg_w, vsg_b, slot_bias);
    ln_t2_k<<<NTOK, 256, 0, stream>>>(x, gamma, beta, slot_bias, img_n, t2);

    // t1 = img_n @ mu_p^T : (32768x768) x (256x768)^T -> logits fp32 (ldc=132)
    mfma2(stream, 2, NTOK / 128, 1, 0,
          img_n, 0, DIM, NTOK, mu_p, 0, DIM, 256, nullptr, 0,
          logits, 0, ESL, BIGI, 0, NTOK, ESL, DIM, 0, 0, 0);

    // fused mask + combine + dispatch (one block per batch)
    softmax_fused_k<<<NB, 256, 0, stream>>>(logits, t2, aw, scale, dT16, comb_p);

    // slot_in(e, b*44+s, d) bf16 = dT16[b](132x128) @ imgT[b]^T ; M=132 (clamped), batch=NB
    mfma2(stream, DIM / 128, 2, NB, 0,
          dT16, (long long)ESL * NIMG, NIMG, ESL,
          imgT, (long long)DIM * NIMG, NIMG, DIM, nullptr, 0,
          slot_in, (long long)NS * DIM, DIM, NS, NB * NS,
          ESL, DIM, NIMG, 0, 1, 0);

    // h(e) = gelu(slot_in(e) @ w1t(e)^T + b1(e)) : M=11264, N=1024, K=768
    // order 0: the 8 x-blocks sharing an A(slot_in)-panel are consecutive -> same XCD L2
    mfma2(stream, NH / 128, NB * NS / 128, NE, 0,
          slot_in, (long long)NB * NS * DIM, DIM, NB * NS,
          w1t, (long long)NH * DIM, DIM, NH, b1, NH,
          h, (long long)NB * NS * NH, NH, BIGI, 0,
          NB * NS, NH, DIM, 1, 1, 0);

    // zero K-pad cols [132,160) of slot_outT (imgT dead now; safe before slot_out GEMM)
    zero_pad_k<<<(NB * DIM * (KPAD - ESL) + 255) / 256, 256, 0, stream>>>(slot_outT);

    // slot_outT[b](768 x 160) bf16 computed DIRECTLY transposed:
    // C(row=d, col=b*44+s) = w2t(e) @ h(e)^T + b2(e)[d]
    // order 1: the 6 y-blocks sharing a B(h)-panel are consecutive -> same XCD L2
    mfma2(stream, NB * NS / 128, DIM / 128, NE, 1,
          w2t, (long long)DIM * NH, NH, DIM,
          h, (long long)NB * NS * NH, NH, NB * NS,
          b2, DIM,
          slot_outT, NS, KPAD, NS, (long long)DIM * KPAD,
          DIM, NB * NS, NH, 0, 1, 2);

    // img_out[b](128x768) = comb_p[b](128x160) @ slot_outT[b](768x160)^T -> out rows b*129+1+n
    mfma2(stream, DIM / 128, 1, NB, 0,
          comb_p, (long long)NIMG * KPAD, KPAD, NIMG,
          slot_outT, (long long)DIM * KPAD, KPAD, DIM, nullptr, 0,
          out + DIM, (long long)129 * DIM, DIM, BIGI, 0,
          NIMG, DIM, KPAD, 0, 0, 0);

    // cls path: cls_h = gelu(cls16 @ cw1t^T + cb1) ; cls_out -> out rows b*129
    mfma2(stream, 4 * DIM / 128, NB / 128, 1, 0,
          cls16, 0, DIM, NB, cw1t, 0, DIM, 4 * DIM, cb1, 0,
          cls_h, 0, 4 * DIM, BIGI, 0, NB, 4 * DIM, DIM, 1, 1, 0);
    mfma2(stream, DIM / 128, NB / 128, 1, 0,
          cls_h, 0, 4 * DIM, NB, cw2t, 0, 4 * DIM, DIM, cb2, 0,
          out, 0, DIM, 1, 129, NB, DIM, 4 * DIM, 0, 0, 0);
}